// Round 20
// baseline (130.148 us; speedup 1.0000x reference)
//
#include <hip/hip_runtime.h>
#include <hip/hip_fp16.h>
#include <math.h>

// Capsule dynamic routing, fused-recompute. MFMA einsum, f16 data, fp32 acc.
// B=512, R=1152, C=10, O=16, I=8.
//   iter0: c_ij = 1/10 uniform  -> s0 = 0.1 * sum_r u_hat
//   iter2: b2 = u.(v0+v1)       -> only running vsum kept
// R19 post-mortem: acc 42us with VALU 33% / MFMA 5% / Occ 18% -> serial
// softmax chain exposed at 2 waves/SIMD; pass floor ~15us. f16 partials
// proven correct -> R16's NaN localized to its structure half.
// R20 = R19 + grid 1024 (4 blocks/CU = 4 waves/SIMD): RCHB 9, CHUNK 3
// (15KB LDS), RSLOTS 128 (f16 partials stay 21MB = proven-safe 2.6MB/
// XCD). Only delta vs R19: 4 mapping constants. All else verbatim.

#define R_TOT 1152
#define C_N 10
#define O_N 16
#define I_N 8
#define B_TOT 512
#define RSLOTS 128                              // partial slices
#define RCHB 9                                  // r's per block
#define CHUNK 3                                 // r's per staged chunk
#define NCH 3                                   // chunks per block
#define SEG (B_TOT * C_N * O_N)                 // 81920 elems per partial slice
#define ROWS (C_N * O_N)                        // 160 W rows per r (16B each, f16)
#define CGR (CHUNK * ROWS)                      // 480 rows per chunk

typedef _Float16 v8h __attribute__((ext_vector_type(8)));
typedef float v4f __attribute__((ext_vector_type(4)));
typedef unsigned u32x4 __attribute__((ext_vector_type(4)));

// pack two fp32 -> f16x2 (RTN via __float2half)
__device__ __forceinline__ unsigned packf2(float a, float b) {
  unsigned ua = (unsigned)__half_as_ushort(__float2half(a));
  unsigned ub = (unsigned)__half_as_ushort(__float2half(b));
  return ua | (ub << 16);
}

// x[b][r][i] fp32 -> xt[r][b] as 8 packed f16 (one uint4)
__global__ __launch_bounds__(256) void transpose_x(
    const float* __restrict__ x, uint4* __restrict__ xt)
{
  const int t = blockIdx.x * 256 + threadIdx.x;   // t = b*R_TOT + r
  const int b = t / R_TOT;
  const int r = t - b * R_TOT;
  const float4* src = reinterpret_cast<const float4*>(x) + (size_t)t * 2;
  const float4 a = src[0], c = src[1];
  uint4 o;
  o.x = packf2(a.x, a.y); o.y = packf2(a.z, a.w);
  o.z = packf2(c.x, c.y); o.w = packf2(c.z, c.w);
  xt[(size_t)r * B_TOT + b] = o;
}

// lane map: bq = lane&15 (b within wave's 16), og = lane>>4 (o-quad).
// thread's b = btile*64 + wave*16 + bq; it holds u[c][o=og*4+j] for all c.
// grid 1024: xcd = bid&7, idx = bid>>3 (0..127); rslot = xcd*16+(idx&15),
// btile = idx>>4. Each XCD owns 16 contiguous rslots.
template<bool UNIFORM>
__global__ __launch_bounds__(256, 2) void acc_kernel(
    const uint4* __restrict__ xt, const float* __restrict__ W,
    const float* __restrict__ vsum, _Float16* __restrict__ part)
{
  __shared__ uint4 wbuf[2 * CGR];   // 15 KB: two 3-slab f16 chunks, LINEAR

  const int tid  = threadIdx.x;
  const int wave = tid >> 6;
  const int lane = tid & 63;
  const int bq   = lane & 15;
  const int og   = lane >> 4;
  const bool lo32 = (lane < 32);
  const int og8  = (og & 1) * 8;          // byte offset of this lane's 8B k-slice

  const int bid   = blockIdx.x;
  const int xcd   = bid & 7;
  const int idx   = bid >> 3;             // 0..127
  const int rslot = xcd * 16 + (idx & 15);
  const int btile = idx >> 4;             // 0..7

  const int b  = btile * 64 + wave * 16 + bq;
  const int r0 = rslot * RCHB;

  // linear staging: chunk rows are contiguous in W (3 consecutive r slabs)
  auto stage = [&](int ci, int buf) {
    const int rbase = r0 + ci * CHUNK;
    #pragma unroll 1
    for (int g = tid; g < CGR; g += 256) {
      const float4* wsrc = reinterpret_cast<const float4*>(W)
                         + ((size_t)rbase * ROWS + g) * 2;
      const float4 a = wsrc[0], c4 = wsrc[1];
      uint4 v;
      v.x = packf2(a.x, a.y);  v.y = packf2(a.z, a.w);
      v.z = packf2(c4.x, c4.y); v.w = packf2(c4.z, c4.w);
      wbuf[buf * CGR + g] = v;
    }
  };

  // x fragment: lanes 0-31 carry the real k-slice (8B of xt row), rest zero
  auto xload = [&](int r) -> uint2 {
    uint2 v; v.x = 0u; v.y = 0u;
    if (lo32)
      v = *reinterpret_cast<const uint2*>(
          reinterpret_cast<const char*>(xt + (size_t)r * B_TOT + b) + og8);
    return v;
  };

  float vf[C_N][4];
  if constexpr (!UNIFORM) {
    #pragma unroll
    for (int c = 0; c < C_N; ++c) {
      const float4 tv = *reinterpret_cast<const float4*>(
          &vsum[((size_t)b * C_N + c) * O_N + og * 4]);
      vf[c][0] = tv.x; vf[c][1] = tv.y; vf[c][2] = tv.z; vf[c][3] = tv.w;
    }
  }

  float sacc[C_N][4];
  #pragma unroll
  for (int c = 0; c < C_N; ++c)
    #pragma unroll
    for (int j = 0; j < 4; ++j) sacc[c][j] = 0.0f;

  uint2 xc, xn;
  stage(0, 0);
  xc = xload(r0);
  __syncthreads();

  #pragma unroll 1
  for (int ci = 0; ci < NCH; ++ci) {
    if (ci + 1 < NCH) stage(ci + 1, (ci + 1) & 1);
    const int sb = (ci & 1) * CGR;
    #pragma unroll 1
    for (int rr = 0; rr < CHUNK; ++rr) {
      const int rl = ci * CHUNK + rr;
      const int rn = (rl + 1 < RCHB) ? rl + 1 : rl;
      xn = xload(r0 + rn);                // prefetch next x under compute

      // ---- MFMA einsum: u[c][j] for this lane's (b, og) ----
      u32x4 bxv = {xc.x, xc.y, 0u, 0u};   // B frag: k-slice in regs0-1, rest 0
      const v8h bf = __builtin_bit_cast(v8h, bxv);
      const char* wb = reinterpret_cast<const char*>(&wbuf[sb + rr * ROWS]);

      float u[C_N][4];
      #pragma unroll
      for (int cg = 0; cg < 2; ++cg) {
        uint2 w8[5];
        #pragma unroll
        for (int c5 = 0; c5 < 5; ++c5) { w8[c5].x = 0u; w8[c5].y = 0u; }
        if (lo32) {
          #pragma unroll
          for (int c5 = 0; c5 < 5; ++c5) {
            const int c = cg * 5 + c5;
            w8[c5] = *reinterpret_cast<const uint2*>(
                wb + (c * 16 + bq) * 16 + og8);
          }
        }
        #pragma unroll
        for (int c5 = 0; c5 < 5; ++c5) {
          u32x4 axv = {w8[c5].x, w8[c5].y, 0u, 0u};
          v4f d = __builtin_amdgcn_mfma_f32_16x16x32_f16(
              __builtin_bit_cast(v8h, axv), bf,
              (v4f){0.f, 0.f, 0.f, 0.f}, 0, 0, 0);
          const int c = cg * 5 + c5;
          u[c][0] = d[0]; u[c][1] = d[1]; u[c][2] = d[2]; u[c][3] = d[3];
        }
      }

      // ---- routing update ----
      if constexpr (UNIFORM) {
        #pragma unroll
        for (int c = 0; c < C_N; ++c)
          #pragma unroll
          for (int j = 0; j < 4; ++j) sacc[c][j] += u[c][j];
      } else {
        float bij[C_N];
        #pragma unroll
        for (int c = 0; c < C_N; ++c) {
          float a = u[c][0] * vf[c][0] + u[c][1] * vf[c][1]
                  + u[c][2] * vf[c][2] + u[c][3] * vf[c][3];
          a += __shfl_xor(a, 16);         // combine og pairs
          a += __shfl_xor(a, 32);         // combine all 4 og
          bij[c] = a;
        }
        float m = bij[0];
        #pragma unroll
        for (int c = 1; c < C_N; ++c) m = fmaxf(m, bij[c]);
        float e[C_N];
        float den = 0.0f;
        #pragma unroll
        for (int c = 0; c < C_N; ++c) { e[c] = __expf(bij[c] - m); den += e[c]; }
        const float inv = __builtin_amdgcn_rcpf(den);
        #pragma unroll
        for (int c = 0; c < C_N; ++c) {
          const float cw = e[c] * inv;
          #pragma unroll
          for (int j = 0; j < 4; ++j) sacc[c][j] += cw * u[c][j];
        }
      }
      xc = xn;
    }
    __syncthreads();
  }

  // f16 partial store: one 8B packed write per c
  const float scale = UNIFORM ? 0.1f : 1.0f;
  _Float16* pb = part + (size_t)rslot * SEG;
  #pragma unroll
  for (int c = 0; c < C_N; ++c) {
    uint2 v;
    v.x = packf2(sacc[c][0] * scale, sacc[c][1] * scale);
    v.y = packf2(sacc[c][2] * scale, sacc[c][3] * scale);
    *reinterpret_cast<uint2*>(
        &pb[((size_t)b * C_N + c) * O_N + og * 4]) = v;
  }
}

// reduce over rslots (f16 partials, fp32 sum) + squash over O=16 per (b,c).
// grid = SEG/64 blocks. MODE 0: vsum = v ; 1: vsum += v ; 2: out = v
template<int MODE>
__global__ __launch_bounds__(256) void reduce_squash(
    const _Float16* __restrict__ part, int nrt,
    float* __restrict__ vsum, float* __restrict__ out)
{
  __shared__ float lds[4][64];
  const int tid = threadIdx.x;
  const int l   = tid & 63;
  const int q   = tid >> 6;
  const int j   = blockIdx.x * 64 + l;
  const _Float16* p = part + j;
  float sv = 0.0f;
  #pragma unroll 4
  for (int rt = q; rt < nrt; rt += 4) sv += (float)p[(size_t)rt * SEG];
  lds[q][l] = sv;
  __syncthreads();
  if (q == 0) {
    sv = lds[0][l] + lds[1][l] + lds[2][l] + lds[3][l];
    float sq = sv * sv;
    sq += __shfl_xor(sq, 1);
    sq += __shfl_xor(sq, 2);
    sq += __shfl_xor(sq, 4);
    sq += __shfl_xor(sq, 8);
    const float scale = sq / (1.0f + sq) * rsqrtf(sq + 1e-8f);
    const float v = scale * sv;
    if constexpr (MODE == 0)      vsum[j] = v;
    else if constexpr (MODE == 1) vsum[j] += v;
    else                          out[j] = v;
  }
}

extern "C" void kernel_launch(void* const* d_in, const int* in_sizes, int n_in,
                              void* d_out, int out_size, void* d_ws, size_t ws_size,
                              hipStream_t stream) {
  (void)in_sizes; (void)n_in; (void)out_size; (void)ws_size;
  const float* x = (const float*)d_in[0];
  const float* W = (const float*)d_in[1];
  float* out  = (float*)d_out;   // doubles as vsum; fully rewritten with v2
  _Float16* part = (_Float16*)d_ws;                       // 128*81920*2B = 21.0 MB
  uint4* xt = reinterpret_cast<uint4*>(part + (size_t)RSLOTS * SEG);  // 9.4 MB f16

  const dim3 blk(256), accGrid(8 * RSLOTS), sqGrid(SEG / 64);

  hipLaunchKernelGGL(transpose_x, dim3((B_TOT * R_TOT) / 256), blk, 0, stream, x, xt);

  // iter 0: uniform coefficients (softmax of zeros)
  hipLaunchKernelGGL((acc_kernel<true>),  accGrid, blk, 0, stream, xt, W, out, part);
  hipLaunchKernelGGL((reduce_squash<0>),  sqGrid,  blk, 0, stream, part, RSLOTS, out, out);  // vsum = v0
  // iter 1
  hipLaunchKernelGGL((acc_kernel<false>), accGrid, blk, 0, stream, xt, W, out, part);
  hipLaunchKernelGGL((reduce_squash<1>),  sqGrid,  blk, 0, stream, part, RSLOTS, out, out);  // vsum = v0+v1
  // iter 2
  hipLaunchKernelGGL((acc_kernel<false>), accGrid, blk, 0, stream, xt, W, out, part);
  hipLaunchKernelGGL((reduce_squash<2>),  sqGrid,  blk, 0, stream, part, RSLOTS, out, out);  // out = v2
}

// Round 22
// 104.987 us; speedup vs baseline: 1.2397x; 1.2397x over previous
//
#include <hip/hip_runtime.h>
#include <hip/hip_fp16.h>
#include <math.h>

// Capsule dynamic routing, fused-recompute. MFMA einsum, f16 data, fp32 acc.
// B=512, R=1152, C=10, O=16, I=8.
//   iter0: c_ij = 1/10 uniform  -> s0 = 0.1 * sum_r u_hat
//   iter2: b2 = u.(v0+v1)       -> only running vsum kept
// R21 post-mortem: cooperative fused kernel never ran (absmax=max|ref|,
// out=0) — co-residency check likely rejected 512 blocks at the fused
// kernel's higher VGPR count. Abandoned; back to R18 (118.4us).
// R22 = R18 + ONE change: drop transpose_x + xt. Each lane's x-need is
// exactly one aligned float4 of natural-layout x (16B at (og&1)*16), so
// load fp32 directly + 2 in-register packf2. Removes the ~6us transpose
// dispatch and its boundary; x loads stay one-r-ahead prefetched.

#define R_TOT 1152
#define C_N 10
#define O_N 16
#define I_N 8
#define B_TOT 512
#define RT 64                                   // rtile count (partial slices)
#define RCHB 18                                 // r's per block
#define CHUNK 6                                 // r's per staged chunk
#define NCH 3                                   // chunks per block
#define SEG (B_TOT * C_N * O_N)                 // 81920 floats per partial slice
#define ROWS (C_N * O_N)                        // 160 W rows per r (16B each, f16)
#define CGR (CHUNK * ROWS)                      // 960 rows per chunk

typedef _Float16 v8h __attribute__((ext_vector_type(8)));
typedef float v4f __attribute__((ext_vector_type(4)));
typedef unsigned u32x4 __attribute__((ext_vector_type(4)));

// pack two fp32 -> f16x2 (RTN via __float2half)
__device__ __forceinline__ unsigned packf2(float a, float b) {
  unsigned ua = (unsigned)__half_as_ushort(__float2half(a));
  unsigned ub = (unsigned)__half_as_ushort(__float2half(b));
  return ua | (ub << 16);
}

// lane map: bq = lane&15 (b within wave's 16), og = lane>>4 (o-quad).
// thread's b = btile*64 + wave*16 + bq; it holds u[c][o=og*4+j] for all c.
// grid 512: xcd = bid&7, idx = bid>>3; rtile = xcd*8+(idx&7), btile = idx>>3.
template<bool UNIFORM>
__global__ __launch_bounds__(256, 2) void acc_kernel(
    const float* __restrict__ x, const float* __restrict__ W,
    const float* __restrict__ vsum, float* __restrict__ part)
{
  __shared__ uint4 wbuf[2 * CGR];   // 30 KB: two 6-slab f16 chunks, LINEAR

  const int tid  = threadIdx.x;
  const int wave = tid >> 6;
  const int lane = tid & 63;
  const int bq   = lane & 15;
  const int og   = lane >> 4;
  const bool lo32 = (lane < 32);

  const int bid   = blockIdx.x;
  const int xcd   = bid & 7;
  const int idx   = bid >> 3;             // 0..63
  const int rtile = xcd * 8 + (idx & 7);
  const int btile = idx >> 3;             // 0..7

  const int b  = btile * 64 + wave * 16 + bq;
  const int r0 = rtile * RCHB;
  const int og8 = (og & 1) * 8;           // byte offset of this lane's 8B k-slice

  // linear staging: chunk rows are contiguous in W (6 consecutive r slabs)
  auto stage = [&](int ci, int buf) {
    const int rbase = r0 + ci * CHUNK;
    #pragma unroll 1
    for (int g = tid; g < CGR; g += 256) {
      const float4* wsrc = reinterpret_cast<const float4*>(W)
                         + ((size_t)rbase * ROWS + g) * 2;
      const float4 a = wsrc[0], c4 = wsrc[1];
      uint4 v;
      v.x = packf2(a.x, a.y);  v.y = packf2(a.z, a.w);
      v.z = packf2(c4.x, c4.y); v.w = packf2(c4.z, c4.w);
      wbuf[buf * CGR + g] = v;
    }
  };

  // x fragment: lanes 0-31 load one aligned float4 of natural-layout x
  // (their 4-elem i-slice) and convert in-register; lanes 32-63 zero.
  auto xload = [&](int r) -> uint2 {
    uint2 v; v.x = 0u; v.y = 0u;
    if (lo32) {
      const float4 xv = *reinterpret_cast<const float4*>(
          &x[((size_t)b * R_TOT + r) * I_N + (og & 1) * 4]);
      v.x = packf2(xv.x, xv.y);
      v.y = packf2(xv.z, xv.w);
    }
    return v;
  };

  float vf[C_N][4];
  if constexpr (!UNIFORM) {
    #pragma unroll
    for (int c = 0; c < C_N; ++c) {
      const float4 tv = *reinterpret_cast<const float4*>(
          &vsum[((size_t)b * C_N + c) * O_N + og * 4]);
      vf[c][0] = tv.x; vf[c][1] = tv.y; vf[c][2] = tv.z; vf[c][3] = tv.w;
    }
  }

  float sacc[C_N][4];
  #pragma unroll
  for (int c = 0; c < C_N; ++c)
    #pragma unroll
    for (int j = 0; j < 4; ++j) sacc[c][j] = 0.0f;

  uint2 xc, xn;
  stage(0, 0);
  xc = xload(r0);
  __syncthreads();

  #pragma unroll 1
  for (int ci = 0; ci < NCH; ++ci) {
    if (ci + 1 < NCH) stage(ci + 1, (ci + 1) & 1);
    const int sb = (ci & 1) * CGR;
    #pragma unroll 1
    for (int rr = 0; rr < CHUNK; ++rr) {
      const int rl = ci * CHUNK + rr;
      const int rn = (rl + 1 < RCHB) ? rl + 1 : rl;
      xn = xload(r0 + rn);                // prefetch next x under compute

      // ---- MFMA einsum: u[c][j] for this lane's (b, og) ----
      u32x4 bxv = {xc.x, xc.y, 0u, 0u};   // B frag: k-slice in regs0-1, rest 0
      const v8h bf = __builtin_bit_cast(v8h, bxv);
      const char* wb = reinterpret_cast<const char*>(&wbuf[sb + rr * ROWS]);

      float u[C_N][4];
      #pragma unroll
      for (int cg = 0; cg < 2; ++cg) {
        uint2 w8[5];
        #pragma unroll
        for (int c5 = 0; c5 < 5; ++c5) { w8[c5].x = 0u; w8[c5].y = 0u; }
        if (lo32) {
          #pragma unroll
          for (int c5 = 0; c5 < 5; ++c5) {
            const int c = cg * 5 + c5;
            w8[c5] = *reinterpret_cast<const uint2*>(
                wb + (c * 16 + bq) * 16 + og8);
          }
        }
        #pragma unroll
        for (int c5 = 0; c5 < 5; ++c5) {
          u32x4 axv = {w8[c5].x, w8[c5].y, 0u, 0u};
          v4f d = __builtin_amdgcn_mfma_f32_16x16x32_f16(
              __builtin_bit_cast(v8h, axv), bf,
              (v4f){0.f, 0.f, 0.f, 0.f}, 0, 0, 0);
          const int c = cg * 5 + c5;
          u[c][0] = d[0]; u[c][1] = d[1]; u[c][2] = d[2]; u[c][3] = d[3];
        }
      }

      // ---- routing update ----
      if constexpr (UNIFORM) {
        #pragma unroll
        for (int c = 0; c < C_N; ++c)
          #pragma unroll
          for (int j = 0; j < 4; ++j) sacc[c][j] += u[c][j];
      } else {
        float bij[C_N];
        #pragma unroll
        for (int c = 0; c < C_N; ++c) {
          float a = u[c][0] * vf[c][0] + u[c][1] * vf[c][1]
                  + u[c][2] * vf[c][2] + u[c][3] * vf[c][3];
          a += __shfl_xor(a, 16);         // combine og pairs
          a += __shfl_xor(a, 32);         // combine all 4 og
          bij[c] = a;
        }
        float m = bij[0];
        #pragma unroll
        for (int c = 1; c < C_N; ++c) m = fmaxf(m, bij[c]);
        float e[C_N];
        float den = 0.0f;
        #pragma unroll
        for (int c = 0; c < C_N; ++c) { e[c] = __expf(bij[c] - m); den += e[c]; }
        const float inv = __builtin_amdgcn_rcpf(den);
        #pragma unroll
        for (int c = 0; c < C_N; ++c) {
          const float cw = e[c] * inv;
          #pragma unroll
          for (int j = 0; j < 4; ++j) sacc[c][j] += cw * u[c][j];
        }
      }
      xc = xn;
    }
    __syncthreads();
  }

  // fp32 float4 partial store
  const float scale = UNIFORM ? 0.1f : 1.0f;
  float* pb = part + (size_t)rtile * SEG;
  #pragma unroll
  for (int c = 0; c < C_N; ++c) {
    float4 v;
    v.x = sacc[c][0] * scale; v.y = sacc[c][1] * scale;
    v.z = sacc[c][2] * scale; v.w = sacc[c][3] * scale;
    *reinterpret_cast<float4*>(
        &pb[((size_t)b * C_N + c) * O_N + og * 4]) = v;
  }
}

// reduce over rtiles + squash over O=16 per (b,c). grid = SEG/64 blocks.
// MODE 0: vsum = v ; MODE 1: vsum += v ; MODE 2: out = v
template<int MODE>
__global__ __launch_bounds__(256) void reduce_squash(
    const float* __restrict__ part, int nrt,
    float* __restrict__ vsum, float* __restrict__ out)
{
  __shared__ float lds[4][64];
  const int tid = threadIdx.x;
  const int l   = tid & 63;
  const int q   = tid >> 6;
  const int j   = blockIdx.x * 64 + l;
  const float* p = part + j;
  float sv = 0.0f;
  #pragma unroll 4
  for (int rt = q; rt < nrt; rt += 4) sv += p[(size_t)rt * SEG];
  lds[q][l] = sv;
  __syncthreads();
  if (q == 0) {
    sv = lds[0][l] + lds[1][l] + lds[2][l] + lds[3][l];
    float sq = sv * sv;
    sq += __shfl_xor(sq, 1);
    sq += __shfl_xor(sq, 2);
    sq += __shfl_xor(sq, 4);
    sq += __shfl_xor(sq, 8);
    const float scale = sq / (1.0f + sq) * rsqrtf(sq + 1e-8f);
    const float v = scale * sv;
    if constexpr (MODE == 0)      vsum[j] = v;
    else if constexpr (MODE == 1) vsum[j] += v;
    else                          out[j] = v;
  }
}

extern "C" void kernel_launch(void* const* d_in, const int* in_sizes, int n_in,
                              void* d_out, int out_size, void* d_ws, size_t ws_size,
                              hipStream_t stream) {
  (void)in_sizes; (void)n_in; (void)out_size; (void)ws_size;
  const float* x = (const float*)d_in[0];
  const float* W = (const float*)d_in[1];
  float* out  = (float*)d_out;   // doubles as vsum; fully rewritten with v2
  float* part = (float*)d_ws;    // RT * SEG floats = 21 MB

  const dim3 blk(256), accGrid(8 * RT), sqGrid(SEG / 64);

  // iter 0: uniform coefficients (softmax of zeros)
  hipLaunchKernelGGL((acc_kernel<true>),  accGrid, blk, 0, stream, x, W, out, part);
  hipLaunchKernelGGL((reduce_squash<0>),  sqGrid,  blk, 0, stream, part, RT, out, out);  // vsum = v0
  // iter 1
  hipLaunchKernelGGL((acc_kernel<false>), accGrid, blk, 0, stream, x, W, out, part);
  hipLaunchKernelGGL((reduce_squash<1>),  sqGrid,  blk, 0, stream, part, RT, out, out);  // vsum = v0+v1
  // iter 2
  hipLaunchKernelGGL((acc_kernel<false>), accGrid, blk, 0, stream, x, W, out, part);
  hipLaunchKernelGGL((reduce_squash<2>),  sqGrid,  blk, 0, stream, part, RT, out, out);  // out = v2
}

// Round 23
// 104.454 us; speedup vs baseline: 1.2460x; 1.0051x over previous
//
#include <hip/hip_runtime.h>
#include <hip/hip_fp16.h>
#include <math.h>

// Capsule dynamic routing, fused-recompute. MFMA einsum, f16 data, fp32 acc.
// B=512, R=1152, C=10, O=16, I=8.
//   iter0: c_ij = 1/10 uniform  -> s0 = 0.1 * sum_r u_hat
//   iter2: b2 = u.(v0+v1)       -> only running vsum kept
// R22 (WIN, 105.0us): transpose dropped, natural-x float4 + in-reg pack.
// R20-null diagnosis: doubling waves left wall+VALU%+MFMA% unchanged ->
// a hidden pipe is saturated: DS issue (~32 DS ops/wave-iter: 10 ds_read
// + 20 ds_bpermute from __shfl_xor(16/32) + staging ~= 23us/CU = acc wall).
// R23 = R22 + ONE change: agreement o-reduce via v_permlane16/32_swap
// (VALU pipe, gfx950) instead of shfl_xor -> 20 DS ops/iter removed in
// passes 1-2. swap(a,a) returns pair whose sum is the xor-group sums;
// identical add order -> bitwise-identical result. __has_builtin fallback.

#define R_TOT 1152
#define C_N 10
#define O_N 16
#define I_N 8
#define B_TOT 512
#define RT 64                                   // rtile count (partial slices)
#define RCHB 18                                 // r's per block
#define CHUNK 6                                 // r's per staged chunk
#define NCH 3                                   // chunks per block
#define SEG (B_TOT * C_N * O_N)                 // 81920 floats per partial slice
#define ROWS (C_N * O_N)                        // 160 W rows per r (16B each, f16)
#define CGR (CHUNK * ROWS)                      // 960 rows per chunk

typedef _Float16 v8h __attribute__((ext_vector_type(8)));
typedef float v4f __attribute__((ext_vector_type(4)));
typedef unsigned u32x4 __attribute__((ext_vector_type(4)));

// pack two fp32 -> f16x2 (RTN via __float2half)
__device__ __forceinline__ unsigned packf2(float a, float b) {
  unsigned ua = (unsigned)__half_as_ushort(__float2half(a));
  unsigned ub = (unsigned)__half_as_ushort(__float2half(b));
  return ua | (ub << 16);
}

// o-reduce across the 4 og groups (lanes l, l^16, l^32, l^48) on the
// VALU pipe via permlane swaps; falls back to shfl_xor (DS pipe).
__device__ __forceinline__ float oreduce(float a) {
#if __has_builtin(__builtin_amdgcn_permlane16_swap) && \
    __has_builtin(__builtin_amdgcn_permlane32_swap)
  typedef unsigned uv2 __attribute__((ext_vector_type(2)));
  unsigned au = __float_as_uint(a);
  uv2 t = __builtin_amdgcn_permlane16_swap(au, au, false, false);
  const float s16 = __uint_as_float(t.x) + __uint_as_float(t.y);
  unsigned su = __float_as_uint(s16);
  uv2 t2 = __builtin_amdgcn_permlane32_swap(su, su, false, false);
  return __uint_as_float(t2.x) + __uint_as_float(t2.y);
#else
  a += __shfl_xor(a, 16);
  a += __shfl_xor(a, 32);
  return a;
#endif
}

// lane map: bq = lane&15 (b within wave's 16), og = lane>>4 (o-quad).
// thread's b = btile*64 + wave*16 + bq; it holds u[c][o=og*4+j] for all c.
// grid 512: xcd = bid&7, idx = bid>>3; rtile = xcd*8+(idx&7), btile = idx>>3.
template<bool UNIFORM>
__global__ __launch_bounds__(256, 2) void acc_kernel(
    const float* __restrict__ x, const float* __restrict__ W,
    const float* __restrict__ vsum, float* __restrict__ part)
{
  __shared__ uint4 wbuf[2 * CGR];   // 30 KB: two 6-slab f16 chunks, LINEAR

  const int tid  = threadIdx.x;
  const int wave = tid >> 6;
  const int lane = tid & 63;
  const int bq   = lane & 15;
  const int og   = lane >> 4;
  const bool lo32 = (lane < 32);

  const int bid   = blockIdx.x;
  const int xcd   = bid & 7;
  const int idx   = bid >> 3;             // 0..63
  const int rtile = xcd * 8 + (idx & 7);
  const int btile = idx >> 3;             // 0..7

  const int b  = btile * 64 + wave * 16 + bq;
  const int r0 = rtile * RCHB;
  const int og8 = (og & 1) * 8;           // byte offset of this lane's 8B k-slice

  // linear staging: chunk rows are contiguous in W (6 consecutive r slabs)
  auto stage = [&](int ci, int buf) {
    const int rbase = r0 + ci * CHUNK;
    #pragma unroll 1
    for (int g = tid; g < CGR; g += 256) {
      const float4* wsrc = reinterpret_cast<const float4*>(W)
                         + ((size_t)rbase * ROWS + g) * 2;
      const float4 a = wsrc[0], c4 = wsrc[1];
      uint4 v;
      v.x = packf2(a.x, a.y);  v.y = packf2(a.z, a.w);
      v.z = packf2(c4.x, c4.y); v.w = packf2(c4.z, c4.w);
      wbuf[buf * CGR + g] = v;
    }
  };

  // x fragment: lanes 0-31 load one aligned float4 of natural-layout x
  // (their 4-elem i-slice) and convert in-register; lanes 32-63 zero.
  auto xload = [&](int r) -> uint2 {
    uint2 v; v.x = 0u; v.y = 0u;
    if (lo32) {
      const float4 xv = *reinterpret_cast<const float4*>(
          &x[((size_t)b * R_TOT + r) * I_N + (og & 1) * 4]);
      v.x = packf2(xv.x, xv.y);
      v.y = packf2(xv.z, xv.w);
    }
    return v;
  };

  float vf[C_N][4];
  if constexpr (!UNIFORM) {
    #pragma unroll
    for (int c = 0; c < C_N; ++c) {
      const float4 tv = *reinterpret_cast<const float4*>(
          &vsum[((size_t)b * C_N + c) * O_N + og * 4]);
      vf[c][0] = tv.x; vf[c][1] = tv.y; vf[c][2] = tv.z; vf[c][3] = tv.w;
    }
  }

  float sacc[C_N][4];
  #pragma unroll
  for (int c = 0; c < C_N; ++c)
    #pragma unroll
    for (int j = 0; j < 4; ++j) sacc[c][j] = 0.0f;

  uint2 xc, xn;
  stage(0, 0);
  xc = xload(r0);
  __syncthreads();

  #pragma unroll 1
  for (int ci = 0; ci < NCH; ++ci) {
    if (ci + 1 < NCH) stage(ci + 1, (ci + 1) & 1);
    const int sb = (ci & 1) * CGR;
    #pragma unroll 1
    for (int rr = 0; rr < CHUNK; ++rr) {
      const int rl = ci * CHUNK + rr;
      const int rn = (rl + 1 < RCHB) ? rl + 1 : rl;
      xn = xload(r0 + rn);                // prefetch next x under compute

      // ---- MFMA einsum: u[c][j] for this lane's (b, og) ----
      u32x4 bxv = {xc.x, xc.y, 0u, 0u};   // B frag: k-slice in regs0-1, rest 0
      const v8h bf = __builtin_bit_cast(v8h, bxv);
      const char* wb = reinterpret_cast<const char*>(&wbuf[sb + rr * ROWS]);

      float u[C_N][4];
      #pragma unroll
      for (int cg = 0; cg < 2; ++cg) {
        uint2 w8[5];
        #pragma unroll
        for (int c5 = 0; c5 < 5; ++c5) { w8[c5].x = 0u; w8[c5].y = 0u; }
        if (lo32) {
          #pragma unroll
          for (int c5 = 0; c5 < 5; ++c5) {
            const int c = cg * 5 + c5;
            w8[c5] = *reinterpret_cast<const uint2*>(
                wb + (c * 16 + bq) * 16 + og8);
          }
        }
        #pragma unroll
        for (int c5 = 0; c5 < 5; ++c5) {
          u32x4 axv = {w8[c5].x, w8[c5].y, 0u, 0u};
          v4f d = __builtin_amdgcn_mfma_f32_16x16x32_f16(
              __builtin_bit_cast(v8h, axv), bf,
              (v4f){0.f, 0.f, 0.f, 0.f}, 0, 0, 0);
          const int c = cg * 5 + c5;
          u[c][0] = d[0]; u[c][1] = d[1]; u[c][2] = d[2]; u[c][3] = d[3];
        }
      }

      // ---- routing update ----
      if constexpr (UNIFORM) {
        #pragma unroll
        for (int c = 0; c < C_N; ++c)
          #pragma unroll
          for (int j = 0; j < 4; ++j) sacc[c][j] += u[c][j];
      } else {
        float bij[C_N];
        #pragma unroll
        for (int c = 0; c < C_N; ++c) {
          const float a = u[c][0] * vf[c][0] + u[c][1] * vf[c][1]
                        + u[c][2] * vf[c][2] + u[c][3] * vf[c][3];
          bij[c] = oreduce(a);            // VALU-pipe cross-lane o-sum
        }
        float m = bij[0];
        #pragma unroll
        for (int c = 1; c < C_N; ++c) m = fmaxf(m, bij[c]);
        float e[C_N];
        float den = 0.0f;
        #pragma unroll
        for (int c = 0; c < C_N; ++c) { e[c] = __expf(bij[c] - m); den += e[c]; }
        const float inv = __builtin_amdgcn_rcpf(den);
        #pragma unroll
        for (int c = 0; c < C_N; ++c) {
          const float cw = e[c] * inv;
          #pragma unroll
          for (int j = 0; j < 4; ++j) sacc[c][j] += cw * u[c][j];
        }
      }
      xc = xn;
    }
    __syncthreads();
  }

  // fp32 float4 partial store
  const float scale = UNIFORM ? 0.1f : 1.0f;
  float* pb = part + (size_t)rtile * SEG;
  #pragma unroll
  for (int c = 0; c < C_N; ++c) {
    float4 v;
    v.x = sacc[c][0] * scale; v.y = sacc[c][1] * scale;
    v.z = sacc[c][2] * scale; v.w = sacc[c][3] * scale;
    *reinterpret_cast<float4*>(
        &pb[((size_t)b * C_N + c) * O_N + og * 4]) = v;
  }
}

// reduce over rtiles + squash over O=16 per (b,c). grid = SEG/64 blocks.
// MODE 0: vsum = v ; MODE 1: vsum += v ; MODE 2: out = v
template<int MODE>
__global__ __launch_bounds__(256) void reduce_squash(
    const float* __restrict__ part, int nrt,
    float* __restrict__ vsum, float* __restrict__ out)
{
  __shared__ float lds[4][64];
  const int tid = threadIdx.x;
  const int l   = tid & 63;
  const int q   = tid >> 6;
  const int j   = blockIdx.x * 64 + l;
  const float* p = part + j;
  float sv = 0.0f;
  #pragma unroll 4
  for (int rt = q; rt < nrt; rt += 4) sv += p[(size_t)rt * SEG];
  lds[q][l] = sv;
  __syncthreads();
  if (q == 0) {
    sv = lds[0][l] + lds[1][l] + lds[2][l] + lds[3][l];
    float sq = sv * sv;
    sq += __shfl_xor(sq, 1);
    sq += __shfl_xor(sq, 2);
    sq += __shfl_xor(sq, 4);
    sq += __shfl_xor(sq, 8);
    const float scale = sq / (1.0f + sq) * rsqrtf(sq + 1e-8f);
    const float v = scale * sv;
    if constexpr (MODE == 0)      vsum[j] = v;
    else if constexpr (MODE == 1) vsum[j] += v;
    else                          out[j] = v;
  }
}

extern "C" void kernel_launch(void* const* d_in, const int* in_sizes, int n_in,
                              void* d_out, int out_size, void* d_ws, size_t ws_size,
                              hipStream_t stream) {
  (void)in_sizes; (void)n_in; (void)out_size; (void)ws_size;
  const float* x = (const float*)d_in[0];
  const float* W = (const float*)d_in[1];
  float* out  = (float*)d_out;   // doubles as vsum; fully rewritten with v2
  float* part = (float*)d_ws;    // RT * SEG floats = 21 MB

  const dim3 blk(256), accGrid(8 * RT), sqGrid(SEG / 64);

  // iter 0: uniform coefficients (softmax of zeros)
  hipLaunchKernelGGL((acc_kernel<true>),  accGrid, blk, 0, stream, x, W, out, part);
  hipLaunchKernelGGL((reduce_squash<0>),  sqGrid,  blk, 0, stream, part, RT, out, out);  // vsum = v0
  // iter 1
  hipLaunchKernelGGL((acc_kernel<false>), accGrid, blk, 0, stream, x, W, out, part);
  hipLaunchKernelGGL((reduce_squash<1>),  sqGrid,  blk, 0, stream, part, RT, out, out);  // vsum = v0+v1
  // iter 2
  hipLaunchKernelGGL((acc_kernel<false>), accGrid, blk, 0, stream, x, W, out, part);
  hipLaunchKernelGGL((reduce_squash<2>),  sqGrid,  blk, 0, stream, part, RT, out, out);  // out = v2
}